// Round 24
// baseline (398.348 us; speedup 1.0000x reference)
//
#include <hip/hip_runtime.h>
#include <hip/hip_bf16.h>
#include <math.h>

// Geometry (fixed by the reference)
#define BB   2
#define CC   64
#define HH   192
#define WW   192
#define HW   (HH*WW)          // 36864
#define HALO 3
#define HP   (HH + 2*HALO)    // 198
#define WP   (WW + 2*HALO)    // 198
#define PLANE (HP*WP)         // 39204

typedef __attribute__((ext_vector_type(8))) _Float16 f16x8;
typedef __attribute__((ext_vector_type(4))) _Float16 f16x4;
typedef __attribute__((ext_vector_type(8))) unsigned short u16x8;
typedef __attribute__((ext_vector_type(4))) float f32x4;

__device__ __forceinline__ float fast_tanh(float x) {
    float e = __expf(2.f * x);
    return 1.f - 2.f * __builtin_amdgcn_rcpf(e + 1.f);
}
__device__ __forceinline__ f16x8 bc16(u16x8 v) { return __builtin_bit_cast(f16x8, v); }

// ---------------------------------------------------------------------------
// Fused pre-conv: relu(Wz @ Xz) -> PADDED fp16 hp8 layout, branch z = blockIdx.z
// ---------------------------------------------------------------------------
__global__ __launch_bounds__(256) void conv_pre_k(
    const float* __restrict__ X0, const float* __restrict__ X1,
    const float* __restrict__ X2,
    const float* __restrict__ W0, const float* __restrict__ W1,
    const float* __restrict__ W2,
    u16x8* __restrict__ hp8all)
{
    __shared__ float wl[64*32];   // [c][o_half]
    int tid = threadIdx.x;
    int oh  = blockIdx.y;
    int z   = blockIdx.z;
    const float* X = (z == 0) ? X0 : ((z == 1) ? X1 : X2);
    const float* W = (z == 0) ? W0 : ((z == 1) ? W1 : W2);
    u16x8* hp8 = hp8all + (size_t)z * ((size_t)BB*8*PLANE);

    #pragma unroll
    for (int n = 0; n < 8; n++) {
        int idx = tid + n*256;
        int op  = idx >> 6, c = idx & 63;
        wl[c*32 + op] = W[(size_t)(oh*32 + op)*64 + c];
    }
    __syncthreads();

    int p  = blockIdx.x*256 + tid;
    int b  = p / HW;
    int pp = p - b*HW;
    size_t base = (size_t)b*CC*HW + pp;

    float acc[32];
    #pragma unroll
    for (int o = 0; o < 32; o++) acc[o] = 0.f;

    #pragma unroll 4
    for (int c = 0; c < 64; c++) {
        float xv = X[base + (size_t)c*HW];
        const float4* w4 = (const float4*)(wl + c*32);
        #pragma unroll
        for (int q = 0; q < 8; q++) {
            float4 w = w4[q];
            acc[4*q+0] = fmaf(w.x, xv, acc[4*q+0]);
            acc[4*q+1] = fmaf(w.y, xv, acc[4*q+1]);
            acc[4*q+2] = fmaf(w.z, xv, acc[4*q+2]);
            acc[4*q+3] = fmaf(w.w, xv, acc[4*q+3]);
        }
    }

    int y = pp / WW, x = pp - y*WW;
    #pragma unroll
    for (int gq = 0; gq < 4; gq++) {
        u16x8 v;
        #pragma unroll
        for (int c = 0; c < 8; c++)
            v[c] = __builtin_bit_cast(unsigned short,
                     (_Float16)fmaxf(acc[gq*8+c], 0.f));
        hp8[(size_t)(b*8 + oh*4 + gq)*PLANE + (size_t)(y+HALO)*WP + (x+HALO)] = v;
    }
}

// ---------------------------------------------------------------------------
// 1x1 conv combine stages (f16 in):
// MODE 1: relu(W@(X*tanh(M)))  -> flat f16
// MODE 2: relu(W@(X*tanh(M))) + Y0+Y1+Y2 -> flat f32 (d_out)
// ---------------------------------------------------------------------------
template<int MODE>
__global__ __launch_bounds__(256) void conv1x1_k(
    const _Float16* __restrict__ Xv, const _Float16* __restrict__ Mv,
    const float* __restrict__ W,
    const float* __restrict__ Y0, const float* __restrict__ Y1,
    const float* __restrict__ Y2,
    void* __restrict__ outv)
{
    __shared__ float wl[64*32];
    int tid = threadIdx.x;
    int oh  = blockIdx.y;
    #pragma unroll
    for (int n = 0; n < 8; n++) {
        int idx = tid + n*256;
        int op  = idx >> 6, c = idx & 63;
        wl[c*32 + op] = W[(size_t)(oh*32 + op)*64 + c];
    }
    __syncthreads();

    int p  = blockIdx.x*256 + tid;
    int b  = p / HW;
    int pp = p - b*HW;
    size_t base = (size_t)b*CC*HW + pp;

    float acc[32];
    #pragma unroll
    for (int o = 0; o < 32; o++) acc[o] = 0.f;

    #pragma unroll 4
    for (int c = 0; c < 64; c++) {
        float xv = (float)Xv[base + (size_t)c*HW];
        xv *= fast_tanh((float)Mv[base + (size_t)c*HW]);
        const float4* w4 = (const float4*)(wl + c*32);
        #pragma unroll
        for (int q = 0; q < 8; q++) {
            float4 w = w4[q];
            acc[4*q+0] = fmaf(w.x, xv, acc[4*q+0]);
            acc[4*q+1] = fmaf(w.y, xv, acc[4*q+1]);
            acc[4*q+2] = fmaf(w.z, xv, acc[4*q+2]);
            acc[4*q+3] = fmaf(w.w, xv, acc[4*q+3]);
        }
    }

    if (MODE == 1) {
        _Float16* op = (_Float16*)outv + base + (size_t)(oh*32)*HW;
        #pragma unroll
        for (int o = 0; o < 32; o++)
            op[(size_t)o*HW] = (_Float16)fmaxf(acc[o], 0.f);
    } else {
        float* op = (float*)outv + base + (size_t)(oh*32)*HW;
        size_t gi = base + (size_t)(oh*32)*HW;
        #pragma unroll
        for (int o = 0; o < 32; o++) {
            float yv = Y0[gi + (size_t)o*HW] + Y1[gi + (size_t)o*HW] + Y2[gi + (size_t)o*HW];
            op[(size_t)o*HW] = fmaxf(acc[o], 0.f) + yv;
        }
    }
}

// ---------------------------------------------------------------------------
// Weight baking (device helpers + single fused kernel, 83 blocks).
// ---------------------------------------------------------------------------
template<int K>
__device__ void bake_wtb_dev(const float* __restrict__ Wreg,
                             f16x8* __restrict__ wtb, int t, int tid)
{
    constexpr int KK = K*K;
    for (int e = tid; e < 512; e += 256) {
        int kk = e >> 8, rem = e & 255;
        int ot = rem >> 6, l = rem & 63;
        int lr = l & 15, lg = l >> 4;
        int o  = ot*16 + lr;
        f16x8 v;
        #pragma unroll
        for (int j = 0; j < 8; j++) {
            int c = kk*32 + lg*8 + j;
            v[j] = (_Float16)Wreg[((size_t)o*CC + c)*KK + t];
        }
        wtb[(size_t)t*512 + e] = v;
    }
}
template<int K>
__device__ void bake_wbg_dev(const float* __restrict__ Woff,
                             const float* __restrict__ Wmod,
                             f16x8* __restrict__ wbg, int pos, int tid)
{
    constexpr int KK  = K*K;
    constexpr int NTF = (3*KK + 15)/16;
    for (int idx = tid; idx < 2*NTF*64; idx += 256) {
        int kk  = idx / (NTF*64);
        int rem = idx - kk*(NTF*64);
        int nt  = rem >> 6;
        int l   = rem & 63;
        int lg  = l >> 4, lr = l & 15;
        int n   = nt*16 + lr;
        f16x8 v;
        #pragma unroll
        for (int j = 0; j < 8; j++) {
            int c = kk*32 + lg*8 + j;
            float w = 0.f;
            if (n < 2*KK)      w = Woff[((size_t)n*CC + c)*KK + pos];
            else if (n < 3*KK) w = Wmod[((size_t)(n - 2*KK)*CC + c)*KK + pos];
            v[j] = (_Float16)w;
        }
        wbg[(size_t)pos*(2*NTF*64) + idx] = v;
    }
}
__global__ __launch_bounds__(256) void bake_all_k(
    const float* wreg7, const float* woff7, const float* wmod7,
    const float* wreg5, const float* woff5, const float* wmod5,
    const float* wreg3, const float* woff3, const float* wmod3,
    f16x8* wtb7, f16x8* wbg7, f16x8* wtb5, f16x8* wbg5,
    f16x8* wtb3, f16x8* wbg3)
{
    int blk = blockIdx.x, tid = threadIdx.x;
    if (blk < 49) {
        bake_wtb_dev<7>(wreg7, wtb7, blk, tid);
        bake_wbg_dev<7>(woff7, wmod7, wbg7, blk, tid);
    } else if (blk < 74) {
        int p = blk - 49;
        bake_wtb_dev<5>(wreg5, wtb5, p, tid);
        bake_wbg_dev<5>(woff5, wmod5, wbg5, p, tid);
    } else {
        int p = blk - 74;
        bake_wtb_dev<3>(wreg3, wtb3, p, tid);
        bake_wbg_dev<3>(woff3, wmod3, wbg3, p, tid);
    }
}

// ---------------------------------------------------------------------------
// Offset + mask KxK conv (r20 winner: PPR-staged LDS B, 2 barriers/round),
// as a device function with externally carved LDS. raw in [0, NBLK).
// ---------------------------------------------------------------------------
template<int K, int MT, int NS, int PPR>
__device__ __forceinline__ void offmod_dev(
    char* smem_raw, int raw,
    const u16x8* __restrict__ hp8,
    const f16x8* __restrict__ wbg,
    const float* __restrict__ Boff, const float* __restrict__ Bmod,
    _Float16* __restrict__ om)
{
    constexpr int PAD  = K/2;
    constexpr int KK   = K*K;
    constexpr int NTF  = (3*KK + 15)/16;
    constexpr int NT   = NTF/NS;
    constexpr int PBB  = HW/(64*MT);
    constexpr int NBLK = BB*PBB*NS;
    constexpr int ROUNDS = (KK + PPR - 1)/PPR;
    constexpr int WELEM  = PPR*2*NT*64;

    f16x8* wl = (f16x8*)smem_raw;

    int swz = (raw & 7)*(NBLK >> 3) + (raw >> 3);
    int ng  = swz % NS;
    int s   = swz / NS;
    int b   = s / PBB;
    int blk = s - b*PBB;

    int tid  = threadIdx.x;
    int wave = tid >> 6;
    int l    = tid & 63;
    int lg   = l >> 4, lr = l & 15;
    int pxw  = blk*(4*MT*16) + wave*(MT*16);
    int y    = pxw / WW, x0 = pxw - y*WW;

    f32x4 acc[MT][NT];
    #pragma unroll
    for (int mt = 0; mt < MT; mt++)
        #pragma unroll
        for (int nt = 0; nt < NT; nt++) acc[mt][nt] = (f32x4)0.f;

    const u16x8* hb = hp8 + (size_t)(b*8)*PLANE;

    for (int r = 0; r < ROUNDS; r++) {
        __syncthreads();
        #pragma unroll
        for (int ii = 0; ii < (WELEM + 255)/256; ii++) {
            int idx = tid + ii*256;
            if (WELEM % 256 == 0 || idx < WELEM) {
                int pp  = idx / (2*NT*64);
                int rem = idx - pp*(2*NT*64);
                int kk  = rem / (NT*64);
                int rem2= rem - kk*(NT*64);
                int nt  = rem2 >> 6;
                int ll  = rem2 & 63;
                int pos = r*PPR + pp;
                if (pos < KK)
                    wl[idx] = wbg[(size_t)pos*(2*NTF*64)
                                  + (size_t)(kk*NTF + ng*NT + nt)*64 + ll];
            }
        }
        __syncthreads();

        #pragma unroll
        for (int pp = 0; pp < PPR; pp++) {
            int pos = r*PPR + pp;
            if (pos >= KK) break;
            int i = pos / K, j = pos - (pos/K)*K;
            int rbase = (y + HALO - PAD + i)*WP + (x0 + HALO - PAD + j);

            #pragma unroll
            for (int kk = 0; kk < 2; kk++) {
                const f16x8* G = (const f16x8*)(hb + (size_t)(kk*4 + lg)*PLANE + rbase);
                f16x8 a[MT];
                #pragma unroll
                for (int mt = 0; mt < MT; mt++) a[mt] = G[mt*16 + lr];
                #pragma unroll
                for (int nt = 0; nt < NT; nt++) {
                    f16x8 bf = wl[((pp*2 + kk)*NT + nt)*64 + l];
                    #pragma unroll
                    for (int mt = 0; mt < MT; mt++)
                        acc[mt][nt] = __builtin_amdgcn_mfma_f32_16x16x32_f16(
                            a[mt], bf, acc[mt][nt], 0, 0, 0);
                }
            }
        }
    }

    #pragma unroll
    for (int nt = 0; nt < NT; nt++) {
        int n = ng*NT*16 + nt*16 + lr;
        if (n < 3*KK) {
            bool is_mask = (n >= 2*KK);
            float bias = is_mask ? Bmod[n - 2*KK] : Boff[n];
            _Float16* dst0 = om + ((size_t)b*3*KK + n)*HW + pxw + lg*4;
            #pragma unroll
            for (int mt = 0; mt < MT; mt++) {
                f32x4 v = acc[mt][nt];
                float v0 = v[0] + bias, v1 = v[1] + bias, v2 = v[2] + bias, v3 = v[3] + bias;
                if (is_mask) {
                    v0 = 2.f * __builtin_amdgcn_rcpf(1.f + __expf(-v0));
                    v1 = 2.f * __builtin_amdgcn_rcpf(1.f + __expf(-v1));
                    v2 = 2.f * __builtin_amdgcn_rcpf(1.f + __expf(-v2));
                    v3 = 2.f * __builtin_amdgcn_rcpf(1.f + __expf(-v3));
                }
                f16x4 o;
                o[0] = (_Float16)v0; o[1] = (_Float16)v1;
                o[2] = (_Float16)v2; o[3] = (_Float16)v3;
                *reinterpret_cast<f16x4*>(dst0 + mt*16) = o;
            }
        }
    }
}

// Fused offmod: all three branches in one launch (K=7 first for backfill).
__global__ __launch_bounds__(256) void offmod_all_k(
    const u16x8* __restrict__ hp8,
    const f16x8* __restrict__ wbg7, const f16x8* __restrict__ wbg5,
    const f16x8* __restrict__ wbg3,
    const float* __restrict__ boff7, const float* __restrict__ bmod7,
    const float* __restrict__ boff5, const float* __restrict__ bmod5,
    const float* __restrict__ boff3, const float* __restrict__ bmod3,
    _Float16* __restrict__ om7, _Float16* __restrict__ om5,
    _Float16* __restrict__ om3)
{
    __shared__ __align__(16) char smem[20480];
    constexpr size_t HPB = (size_t)BB*8*PLANE;
    constexpr int G7 = BB*(HW/128)*2;   // 1152
    constexpr int G5 = BB*(HW/64);      // 1152
    int blk = blockIdx.x;
    if (blk < G7)
        offmod_dev<7,2,2,2>(smem, blk, hp8, wbg7, boff7, bmod7, om7);
    else if (blk < G7 + G5)
        offmod_dev<5,1,1,2>(smem, blk - G7, hp8 + HPB, wbg5, boff5, bmod5, om5);
    else
        offmod_dev<3,2,1,3>(smem, blk - G7 - G5, hp8 + 2*HPB, wbg3, boff3, bmod3, om3);
}

// ---------------------------------------------------------------------------
// Deformable sampling + MFMA channel matmul (r20 winner) as device function
// with carved LDS. r24: window layout [pos][grp] with XOR swizzle
// (slot = grp ^ (pos&7)) — each pixel's 4 group-chunks fill one 128B bank
// frame; consecutive-wf reads hit the theoretical 8-cycle minimum with
// zero conflicts, data-independently.
// ---------------------------------------------------------------------------
template<int K> struct DfmLds {
    static constexpr int HWW = K + 2;
    static constexpr int WWW = 16 + K + 2;
    static constexpr int WIN_B = 8*HWW*WWW*16;
    static constexpr int NPT = K*K*16;
    static constexpr int COORD_B = NPT*8 + NPT*4 + ((NPT*2 + 15)/16)*16;
    static constexpr int RED_B = 2*64*16*4;
    static constexpr int UNION_B = (COORD_B > RED_B ? COORD_B : RED_B);
    static constexpr int TOTAL = WIN_B + UNION_B;
};

template<int K>
__device__ __forceinline__ void deform_dev(
    char* smem_raw, int raw,
    const u16x8* __restrict__ hp8,
    const _Float16* __restrict__ om,
    const f16x8* __restrict__ wtb,
    _Float16* __restrict__ out)
{
    constexpr int PAD = K/2;
    constexpr int KK  = K*K;
    constexpr int NSB = HW/16;
    constexpr int HWW = K + 2;
    constexpr int WWW = 16 + K + 2;
    constexpr int WELEMS = 8*HWW*WWW;
    constexpr int NPT = KK*16;

    u16x8* win = (u16x8*)smem_raw;                    // [pos][grp] swizzled
    char*  ubuf = smem_raw + WELEMS*16;

    f16x4*          hco  = (f16x4*)ubuf;
    unsigned*       gofs = (unsigned*)(ubuf + NPT*8);
    unsigned short* wofs = (unsigned short*)(ubuf + NPT*8 + NPT*4);

    int swz = (raw & 7)*((BB*NSB) >> 3) + (raw >> 3);
    int b = swz / NSB, strip = swz - b*NSB;

    int tid  = threadIdx.x;
    int wave = tid >> 6;
    int l    = tid & 63;
    int lg   = l >> 4;
    int lr   = l & 15;
    int th   = wave & 1;
    int kkh  = wave >> 1;
    int pxbase = strip*16;
    int y    = pxbase / WW;               // uniform: 192 % 16 == 0
    int xs   = pxbase - y*WW;

    int wy0 = y  + HALO - PAD - 1;
    int wx0 = xs + HALO - PAD - 1;

    // ---- stage window (coalesced global order, swizzled LDS write) ----
    {
        const u16x8* hbb = hp8 + (size_t)(b*8)*PLANE;
        for (int idx = tid; idx < WELEMS; idx += 256) {
            int g   = idx / (HWW*WWW);
            int pos = idx - g*(HWW*WWW);
            int r   = pos / WWW;
            int c2  = pos - r*WWW;
            int gy = min(max(wy0 + r, 0), HP-1);
            int gx = min(max(wx0 + c2, 0), WP-1);
            win[pos*8 + (g ^ (pos & 7))] = hbb[(size_t)g*PLANE + gy*WP + gx];
        }
    }
    // ---- precompute coords for all (px, tap) pairs ----
    {
        const _Float16* ob = om + (size_t)b*3*KK*HW + pxbase;
        for (int idx = tid; idx < NPT; idx += 256) {
            int pxl = idx & 15, t = idx >> 4;
            float offy = (float)ob[(size_t)(2*t  )*HW + pxl];
            float offx = (float)ob[(size_t)(2*t+1)*HW + pxl];
            float mk   = (float)ob[(size_t)(2*KK+t)*HW + pxl];
            int i = t / K, j = t - (t/K)*K;
            float py  = (float)(y - PAD + i) + offy;
            float pxf = (float)(xs + pxl - PAD + j) + offx;
            float fy = floorf(py), fx = floorf(pxf);
            float wy1 = py - fy, wx1 = pxf - fx;
            int iy0 = (int)fy, ix0 = (int)fx;
            int Y0 = min(max(iy0, -1), HH) + HALO;   // zero-halo clamp
            int X0 = min(max(ix0, -1), WW) + HALO;
            int ry = Y0 - wy0, rx = X0 - wx0;
            bool in = ((unsigned)ry <= (unsigned)(HWW-2)) &
                      ((unsigned)rx <= (unsigned)(WWW-2));
            f16x4 h;
            h[0] = (_Float16)((1.f-wy1)*(1.f-wx1)*mk);
            h[1] = (_Float16)((1.f-wy1)*wx1*mk);
            h[2] = (_Float16)(wy1*(1.f-wx1)*mk);
            h[3] = (_Float16)(wy1*wx1*mk);
            hco[idx]  = h;
            gofs[idx] = (unsigned)(Y0*WP + X0);
            wofs[idx] = (unsigned short)((ry*WWW + rx) | (in ? 0 : 0x8000));
        }
    }
    __syncthreads();

    int t0 = (KK*th)/2, t1 = (KK*(th+1))/2;

    f32x4 acc[4];
    #pragma unroll
    for (int ot = 0; ot < 4; ot++) acc[ot] = (f32x4)0.f;

    const u16x8* hb = hp8 + (size_t)(b*8 + kkh*4 + lg)*PLANE;
    int grp = kkh*4 + lg;

    #pragma unroll 1
    for (int t = t0; t < t1; t++) {
        int idx = t*16 + lr;
        f16x4 h = hco[idx];
        unsigned short wf = wofs[idx];
        bool in = (wf & 0x8000) == 0;

        f16x8 c0, c1, c2, c3;
        if (__all(in)) {
            int p0 = wf,          p1 = wf + 1;
            int p2 = wf + WWW,    p3 = wf + WWW + 1;
            c0 = bc16(win[p0*8 + (grp ^ (p0 & 7))]);
            c1 = bc16(win[p1*8 + (grp ^ (p1 & 7))]);
            c2 = bc16(win[p2*8 + (grp ^ (p2 & 7))]);
            c3 = bc16(win[p3*8 + (grp ^ (p3 & 7))]);
        } else {
            const u16x8* G = hb + gofs[idx];
            c0 = bc16(G[0]);  c1 = bc16(G[1]);
            c2 = bc16(G[WP]); c3 = bc16(G[WP+1]);
        }

        f16x8 s = c0*h[0] + c1*h[1] + c2*h[2] + c3*h[3];

        const f16x8* bp = wtb + (size_t)t*8*64 + l;
        #pragma unroll
        for (int ot = 0; ot < 4; ot++) {
            acc[ot] = __builtin_amdgcn_mfma_f32_16x16x32_f16(
                s, bp[(size_t)(kkh*4 + ot)*64], acc[ot], 0, 0, 0);
        }
    }

    // ---- two-stage reduce, XOR-swizzled (ubuf reused) ----
    __syncthreads();
    float* redf = (float*)ubuf;   // logical [2][64][16] f32, swizzled px dim
    #define RIDX(tt, o, g)  (((tt)*64 + (o))*16 + (((g) ^ ((o) & 3)) * 4))
    if (kkh == 1) {
        #pragma unroll
        for (int ot = 0; ot < 4; ot++) {
            int o = ot*16 + lr;
            *reinterpret_cast<f32x4*>(&redf[RIDX(th, o, lg)]) = acc[ot];
        }
    }
    __syncthreads();
    if (kkh == 0) {
        #pragma unroll
        for (int ot = 0; ot < 4; ot++) {
            int o = ot*16 + lr;
            acc[ot] += *reinterpret_cast<const f32x4*>(&redf[RIDX(th, o, lg)]);
        }
    }
    __syncthreads();
    if (kkh == 0 && th == 1) {
        #pragma unroll
        for (int ot = 0; ot < 4; ot++) {
            int o = ot*16 + lr;
            *reinterpret_cast<f32x4*>(&redf[RIDX(0, o, lg)]) = acc[ot];
        }
    }
    __syncthreads();
    if (kkh == 0 && th == 0) {
        _Float16* ob = out + (size_t)b*CC*HW + pxbase + lg*4;
        #pragma unroll
        for (int ot = 0; ot < 4; ot++) {
            int o = ot*16 + lr;
            f32x4 rr = *reinterpret_cast<const f32x4*>(&redf[RIDX(0, o, lg)]);
            rr += acc[ot];
            f16x4 v;
            v[0] = (_Float16)rr[0]; v[1] = (_Float16)rr[1];
            v[2] = (_Float16)rr[2]; v[3] = (_Float16)rr[3];
            *reinterpret_cast<f16x4*>(ob + (size_t)o*HW) = v;
        }
    }
    #undef RIDX
}

// Fused deform: all three branches in one launch (K=7 first).
__global__ __launch_bounds__(256, 4) void deform_all_k(
    const u16x8* __restrict__ hp8,
    const _Float16* __restrict__ om7, const _Float16* __restrict__ om5,
    const _Float16* __restrict__ om3,
    const f16x8* __restrict__ wtb7, const f16x8* __restrict__ wtb5,
    const f16x8* __restrict__ wtb3,
    _Float16* __restrict__ aa, _Float16* __restrict__ mm,
    _Float16* __restrict__ sm)
{
    constexpr int DFM_SMEM =
        (DfmLds<7>::TOTAL > DfmLds<5>::TOTAL ?
            (DfmLds<7>::TOTAL > DfmLds<3>::TOTAL ? DfmLds<7>::TOTAL : DfmLds<3>::TOTAL)
          : (DfmLds<5>::TOTAL > DfmLds<3>::TOTAL ? DfmLds<5>::TOTAL : DfmLds<3>::TOTAL));
    __shared__ __align__(16) char smem[DFM_SMEM];
    constexpr size_t HPB = (size_t)BB*8*PLANE;
    constexpr int GD = BB*(HW/16);     // 4608 per branch
    int blk = blockIdx.x;
    if (blk < GD)
        deform_dev<7>(smem, blk, hp8, om7, wtb7, aa);
    else if (blk < 2*GD)
        deform_dev<5>(smem, blk - GD, hp8 + HPB, om5, wtb5, mm);
    else
        deform_dev<3>(smem, blk - 2*GD, hp8 + 2*HPB, om3, wtb3, sm);
}

// ---------------------------------------------------------------------------
// Launch. Workspace (bytes):
//   hp8 x3 : 3 * BB*8*PLANE*16B = ~30.1 MB
//   om7/om5/om3 : 21.7 / 11.1 / 4.0 MB (f16)  [u aliases om7 after deforms]
//   aa/mm/sm : BB*CC*HW*2B each = ~9.4 MB each (f16)
//   weights : ~2.0 MB      total ~97.2 MB
// 6 launches total.
// ---------------------------------------------------------------------------
extern "C" void kernel_launch(void* const* d_in, const int* in_sizes, int n_in,
                              void* d_out, int out_size, void* d_ws, size_t ws_size,
                              hipStream_t stream)
{
    const float* x_max      = (const float*)d_in[0];
    const float* x_mid      = (const float*)d_in[1];
    const float* x_small    = (const float*)d_in[2];
    const float* w_pre_max  = (const float*)d_in[3];
    const float* w_off_max  = (const float*)d_in[4];
    const float* b_off_max  = (const float*)d_in[5];
    const float* w_mod_max  = (const float*)d_in[6];
    const float* b_mod_max  = (const float*)d_in[7];
    const float* w_reg_max  = (const float*)d_in[8];
    const float* w_pre_mid  = (const float*)d_in[9];
    const float* w_off_mid  = (const float*)d_in[10];
    const float* b_off_mid  = (const float*)d_in[11];
    const float* w_mod_mid  = (const float*)d_in[12];
    const float* b_mod_mid  = (const float*)d_in[13];
    const float* w_reg_mid  = (const float*)d_in[14];
    const float* w_pre_small= (const float*)d_in[15];
    const float* w_off_small= (const float*)d_in[16];
    const float* b_off_small= (const float*)d_in[17];
    const float* w_mod_small= (const float*)d_in[18];
    const float* b_mod_small= (const float*)d_in[19];
    const float* w_reg_small= (const float*)d_in[20];
    const float* w1         = (const float*)d_in[21];
    const float* w2         = (const float*)d_in[22];

    float* out = (float*)d_out;
    char*  ws  = (char*)d_ws;

    const size_t HPB = (size_t)BB*8*PLANE;      // u16x8 elems per branch

    u16x8*    hp8 = (u16x8*)ws;                 ws += 3*HPB*16;
    _Float16* om7 = (_Float16*)ws;              ws += (size_t)BB*3*49*HW*2;
    _Float16* om5 = (_Float16*)ws;              ws += (size_t)BB*3*25*HW*2;
    _Float16* om3 = (_Float16*)ws;              ws += (size_t)BB*3*9*HW*2;
    _Float16* aa  = (_Float16*)ws;              ws += (size_t)BB*CC*HW*2;
    _Float16* mm  = (_Float16*)ws;              ws += (size_t)BB*CC*HW*2;
    _Float16* sm  = (_Float16*)ws;              ws += (size_t)BB*CC*HW*2;
    f16x8*    wtb7= (f16x8*)ws;                 ws += (size_t)49*512*16;
    f16x8*    wbg7= (f16x8*)ws;                 ws += (size_t)49*2*10*64*16;
    f16x8*    wtb5= (f16x8*)ws;                 ws += (size_t)25*512*16;
    f16x8*    wbg5= (f16x8*)ws;                 ws += (size_t)25*2*5*64*16;
    f16x8*    wtb3= (f16x8*)ws;                 ws += (size_t)9*512*16;
    f16x8*    wbg3= (f16x8*)ws;
    _Float16* u   = om7;   // om7 dead after deform_all_k

    hipMemsetAsync(hp8, 0, 3*HPB*16, stream);

    const int npix_blocks = (BB*HW)/256;       // 288
    const int off_blocks  = BB*(HW/128)*2 + BB*(HW/64) + BB*(HW/128); // 2880
    const int dfm_blocks  = 3*BB*(HW/16);      // 13824

    bake_all_k<<<83, 256, 0, stream>>>(
        w_reg_max, w_off_max, w_mod_max,
        w_reg_mid, w_off_mid, w_mod_mid,
        w_reg_small, w_off_small, w_mod_small,
        wtb7, wbg7, wtb5, wbg5, wtb3, wbg3);
    conv_pre_k<<<dim3(npix_blocks, 2, 3), 256, 0, stream>>>(
        x_max, x_mid, x_small, w_pre_max, w_pre_mid, w_pre_small, hp8);

    offmod_all_k<<<off_blocks, 256, 0, stream>>>(
        hp8, wbg7, wbg5, wbg3,
        b_off_max, b_mod_max, b_off_mid, b_mod_mid, b_off_small, b_mod_small,
        om7, om5, om3);

    deform_all_k<<<dfm_blocks, 256, 0, stream>>>(
        hp8, om7, om5, om3, wtb7, wtb5, wtb3, aa, mm, sm);

    conv1x1_k<1><<<dim3(npix_blocks,2), 256, 0, stream>>>(aa, mm, w1,
                                                  nullptr, nullptr, nullptr, u);
    conv1x1_k<2><<<dim3(npix_blocks,2), 256, 0, stream>>>(u, sm, w2,
                                                  x_max, x_mid, x_small, out);
}

// Round 25
// 396.006 us; speedup vs baseline: 1.0059x; 1.0059x over previous
//
#include <hip/hip_runtime.h>
#include <hip/hip_bf16.h>
#include <math.h>

// Geometry (fixed by the reference)
#define BB   2
#define CC   64
#define HH   192
#define WW   192
#define HW   (HH*WW)          // 36864
#define HALO 3
#define HP   (HH + 2*HALO)    // 198
#define WP   (WW + 2*HALO)    // 198
#define PLANE (HP*WP)         // 39204

typedef __attribute__((ext_vector_type(8))) _Float16 f16x8;
typedef __attribute__((ext_vector_type(4))) _Float16 f16x4;
typedef __attribute__((ext_vector_type(8))) unsigned short u16x8;
typedef __attribute__((ext_vector_type(4))) float f32x4;

__device__ __forceinline__ float fast_tanh(float x) {
    float e = __expf(2.f * x);
    return 1.f - 2.f * __builtin_amdgcn_rcpf(e + 1.f);
}
__device__ __forceinline__ f16x8 bc16(u16x8 v) { return __builtin_bit_cast(f16x8, v); }

// ---------------------------------------------------------------------------
// Fused pre-conv: relu(Wz @ Xz) -> PADDED fp16 hp8 layout, branch z = blockIdx.z
// ---------------------------------------------------------------------------
__global__ __launch_bounds__(256) void conv_pre_k(
    const float* __restrict__ X0, const float* __restrict__ X1,
    const float* __restrict__ X2,
    const float* __restrict__ W0, const float* __restrict__ W1,
    const float* __restrict__ W2,
    u16x8* __restrict__ hp8all)
{
    __shared__ float wl[64*32];   // [c][o_half]
    int tid = threadIdx.x;
    int oh  = blockIdx.y;
    int z   = blockIdx.z;
    const float* X = (z == 0) ? X0 : ((z == 1) ? X1 : X2);
    const float* W = (z == 0) ? W0 : ((z == 1) ? W1 : W2);
    u16x8* hp8 = hp8all + (size_t)z * ((size_t)BB*8*PLANE);

    #pragma unroll
    for (int n = 0; n < 8; n++) {
        int idx = tid + n*256;
        int op  = idx >> 6, c = idx & 63;
        wl[c*32 + op] = W[(size_t)(oh*32 + op)*64 + c];
    }
    __syncthreads();

    int p  = blockIdx.x*256 + tid;
    int b  = p / HW;
    int pp = p - b*HW;
    size_t base = (size_t)b*CC*HW + pp;

    float acc[32];
    #pragma unroll
    for (int o = 0; o < 32; o++) acc[o] = 0.f;

    #pragma unroll 4
    for (int c = 0; c < 64; c++) {
        float xv = X[base + (size_t)c*HW];
        const float4* w4 = (const float4*)(wl + c*32);
        #pragma unroll
        for (int q = 0; q < 8; q++) {
            float4 w = w4[q];
            acc[4*q+0] = fmaf(w.x, xv, acc[4*q+0]);
            acc[4*q+1] = fmaf(w.y, xv, acc[4*q+1]);
            acc[4*q+2] = fmaf(w.z, xv, acc[4*q+2]);
            acc[4*q+3] = fmaf(w.w, xv, acc[4*q+3]);
        }
    }

    int y = pp / WW, x = pp - y*WW;
    #pragma unroll
    for (int gq = 0; gq < 4; gq++) {
        u16x8 v;
        #pragma unroll
        for (int c = 0; c < 8; c++)
            v[c] = __builtin_bit_cast(unsigned short,
                     (_Float16)fmaxf(acc[gq*8+c], 0.f));
        hp8[(size_t)(b*8 + oh*4 + gq)*PLANE + (size_t)(y+HALO)*WP + (x+HALO)] = v;
    }
}

// ---------------------------------------------------------------------------
// 1x1 conv combine stages (f16 in):
// MODE 1: relu(W@(X*tanh(M)))  -> flat f16
// MODE 2: relu(W@(X*tanh(M))) + Y0+Y1+Y2 -> flat f32 (d_out)
// ---------------------------------------------------------------------------
template<int MODE>
__global__ __launch_bounds__(256) void conv1x1_k(
    const _Float16* __restrict__ Xv, const _Float16* __restrict__ Mv,
    const float* __restrict__ W,
    const float* __restrict__ Y0, const float* __restrict__ Y1,
    const float* __restrict__ Y2,
    void* __restrict__ outv)
{
    __shared__ float wl[64*32];
    int tid = threadIdx.x;
    int oh  = blockIdx.y;
    #pragma unroll
    for (int n = 0; n < 8; n++) {
        int idx = tid + n*256;
        int op  = idx >> 6, c = idx & 63;
        wl[c*32 + op] = W[(size_t)(oh*32 + op)*64 + c];
    }
    __syncthreads();

    int p  = blockIdx.x*256 + tid;
    int b  = p / HW;
    int pp = p - b*HW;
    size_t base = (size_t)b*CC*HW + pp;

    float acc[32];
    #pragma unroll
    for (int o = 0; o < 32; o++) acc[o] = 0.f;

    #pragma unroll 4
    for (int c = 0; c < 64; c++) {
        float xv = (float)Xv[base + (size_t)c*HW];
        xv *= fast_tanh((float)Mv[base + (size_t)c*HW]);
        const float4* w4 = (const float4*)(wl + c*32);
        #pragma unroll
        for (int q = 0; q < 8; q++) {
            float4 w = w4[q];
            acc[4*q+0] = fmaf(w.x, xv, acc[4*q+0]);
            acc[4*q+1] = fmaf(w.y, xv, acc[4*q+1]);
            acc[4*q+2] = fmaf(w.z, xv, acc[4*q+2]);
            acc[4*q+3] = fmaf(w.w, xv, acc[4*q+3]);
        }
    }

    if (MODE == 1) {
        _Float16* op = (_Float16*)outv + base + (size_t)(oh*32)*HW;
        #pragma unroll
        for (int o = 0; o < 32; o++)
            op[(size_t)o*HW] = (_Float16)fmaxf(acc[o], 0.f);
    } else {
        float* op = (float*)outv + base + (size_t)(oh*32)*HW;
        size_t gi = base + (size_t)(oh*32)*HW;
        #pragma unroll
        for (int o = 0; o < 32; o++) {
            float yv = Y0[gi + (size_t)o*HW] + Y1[gi + (size_t)o*HW] + Y2[gi + (size_t)o*HW];
            op[(size_t)o*HW] = fmaxf(acc[o], 0.f) + yv;
        }
    }
}

// ---------------------------------------------------------------------------
// Weight baking (device helpers + single fused kernel, 83 blocks).
// ---------------------------------------------------------------------------
template<int K>
__device__ void bake_wtb_dev(const float* __restrict__ Wreg,
                             f16x8* __restrict__ wtb, int t, int tid)
{
    constexpr int KK = K*K;
    for (int e = tid; e < 512; e += 256) {
        int kk = e >> 8, rem = e & 255;
        int ot = rem >> 6, l = rem & 63;
        int lr = l & 15, lg = l >> 4;
        int o  = ot*16 + lr;
        f16x8 v;
        #pragma unroll
        for (int j = 0; j < 8; j++) {
            int c = kk*32 + lg*8 + j;
            v[j] = (_Float16)Wreg[((size_t)o*CC + c)*KK + t];
        }
        wtb[(size_t)t*512 + e] = v;
    }
}
template<int K>
__device__ void bake_wbg_dev(const float* __restrict__ Woff,
                             const float* __restrict__ Wmod,
                             f16x8* __restrict__ wbg, int pos, int tid)
{
    constexpr int KK  = K*K;
    constexpr int NTF = (3*KK + 15)/16;
    for (int idx = tid; idx < 2*NTF*64; idx += 256) {
        int kk  = idx / (NTF*64);
        int rem = idx - kk*(NTF*64);
        int nt  = rem >> 6;
        int l   = rem & 63;
        int lg  = l >> 4, lr = l & 15;
        int n   = nt*16 + lr;
        f16x8 v;
        #pragma unroll
        for (int j = 0; j < 8; j++) {
            int c = kk*32 + lg*8 + j;
            float w = 0.f;
            if (n < 2*KK)      w = Woff[((size_t)n*CC + c)*KK + pos];
            else if (n < 3*KK) w = Wmod[((size_t)(n - 2*KK)*CC + c)*KK + pos];
            v[j] = (_Float16)w;
        }
        wbg[(size_t)pos*(2*NTF*64) + idx] = v;
    }
}
__global__ __launch_bounds__(256) void bake_all_k(
    const float* wreg7, const float* woff7, const float* wmod7,
    const float* wreg5, const float* woff5, const float* wmod5,
    const float* wreg3, const float* woff3, const float* wmod3,
    f16x8* wtb7, f16x8* wbg7, f16x8* wtb5, f16x8* wbg5,
    f16x8* wtb3, f16x8* wbg3)
{
    int blk = blockIdx.x, tid = threadIdx.x;
    if (blk < 49) {
        bake_wtb_dev<7>(wreg7, wtb7, blk, tid);
        bake_wbg_dev<7>(woff7, wmod7, wbg7, blk, tid);
    } else if (blk < 74) {
        int p = blk - 49;
        bake_wtb_dev<5>(wreg5, wtb5, p, tid);
        bake_wbg_dev<5>(woff5, wmod5, wbg5, p, tid);
    } else {
        int p = blk - 74;
        bake_wtb_dev<3>(wreg3, wtb3, p, tid);
        bake_wbg_dev<3>(woff3, wmod3, wbg3, p, tid);
    }
}

// ---------------------------------------------------------------------------
// Offset + mask KxK conv (r20 winner: PPR-staged LDS B, 2 barriers/round),
// as a device function with externally carved LDS. raw in [0, NBLK).
// ---------------------------------------------------------------------------
template<int K, int MT, int NS, int PPR>
__device__ __forceinline__ void offmod_dev(
    char* smem_raw, int raw,
    const u16x8* __restrict__ hp8,
    const f16x8* __restrict__ wbg,
    const float* __restrict__ Boff, const float* __restrict__ Bmod,
    _Float16* __restrict__ om)
{
    constexpr int PAD  = K/2;
    constexpr int KK   = K*K;
    constexpr int NTF  = (3*KK + 15)/16;
    constexpr int NT   = NTF/NS;
    constexpr int PBB  = HW/(64*MT);
    constexpr int NBLK = BB*PBB*NS;
    constexpr int ROUNDS = (KK + PPR - 1)/PPR;
    constexpr int WELEM  = PPR*2*NT*64;

    f16x8* wl = (f16x8*)smem_raw;

    int swz = (raw & 7)*(NBLK >> 3) + (raw >> 3);
    int ng  = swz % NS;
    int s   = swz / NS;
    int b   = s / PBB;
    int blk = s - b*PBB;

    int tid  = threadIdx.x;
    int wave = tid >> 6;
    int l    = tid & 63;
    int lg   = l >> 4, lr = l & 15;
    int pxw  = blk*(4*MT*16) + wave*(MT*16);
    int y    = pxw / WW, x0 = pxw - y*WW;

    f32x4 acc[MT][NT];
    #pragma unroll
    for (int mt = 0; mt < MT; mt++)
        #pragma unroll
        for (int nt = 0; nt < NT; nt++) acc[mt][nt] = (f32x4)0.f;

    const u16x8* hb = hp8 + (size_t)(b*8)*PLANE;

    for (int r = 0; r < ROUNDS; r++) {
        __syncthreads();
        #pragma unroll
        for (int ii = 0; ii < (WELEM + 255)/256; ii++) {
            int idx = tid + ii*256;
            if (WELEM % 256 == 0 || idx < WELEM) {
                int pp  = idx / (2*NT*64);
                int rem = idx - pp*(2*NT*64);
                int kk  = rem / (NT*64);
                int rem2= rem - kk*(NT*64);
                int nt  = rem2 >> 6;
                int ll  = rem2 & 63;
                int pos = r*PPR + pp;
                if (pos < KK)
                    wl[idx] = wbg[(size_t)pos*(2*NTF*64)
                                  + (size_t)(kk*NTF + ng*NT + nt)*64 + ll];
            }
        }
        __syncthreads();

        #pragma unroll
        for (int pp = 0; pp < PPR; pp++) {
            int pos = r*PPR + pp;
            if (pos >= KK) break;
            int i = pos / K, j = pos - (pos/K)*K;
            int rbase = (y + HALO - PAD + i)*WP + (x0 + HALO - PAD + j);

            #pragma unroll
            for (int kk = 0; kk < 2; kk++) {
                const f16x8* G = (const f16x8*)(hb + (size_t)(kk*4 + lg)*PLANE + rbase);
                f16x8 a[MT];
                #pragma unroll
                for (int mt = 0; mt < MT; mt++) a[mt] = G[mt*16 + lr];
                #pragma unroll
                for (int nt = 0; nt < NT; nt++) {
                    f16x8 bf = wl[((pp*2 + kk)*NT + nt)*64 + l];
                    #pragma unroll
                    for (int mt = 0; mt < MT; mt++)
                        acc[mt][nt] = __builtin_amdgcn_mfma_f32_16x16x32_f16(
                            a[mt], bf, acc[mt][nt], 0, 0, 0);
                }
            }
        }
    }

    #pragma unroll
    for (int nt = 0; nt < NT; nt++) {
        int n = ng*NT*16 + nt*16 + lr;
        if (n < 3*KK) {
            bool is_mask = (n >= 2*KK);
            float bias = is_mask ? Bmod[n - 2*KK] : Boff[n];
            _Float16* dst0 = om + ((size_t)b*3*KK + n)*HW + pxw + lg*4;
            #pragma unroll
            for (int mt = 0; mt < MT; mt++) {
                f32x4 v = acc[mt][nt];
                float v0 = v[0] + bias, v1 = v[1] + bias, v2 = v[2] + bias, v3 = v[3] + bias;
                if (is_mask) {
                    v0 = 2.f * __builtin_amdgcn_rcpf(1.f + __expf(-v0));
                    v1 = 2.f * __builtin_amdgcn_rcpf(1.f + __expf(-v1));
                    v2 = 2.f * __builtin_amdgcn_rcpf(1.f + __expf(-v2));
                    v3 = 2.f * __builtin_amdgcn_rcpf(1.f + __expf(-v3));
                }
                f16x4 o;
                o[0] = (_Float16)v0; o[1] = (_Float16)v1;
                o[2] = (_Float16)v2; o[3] = (_Float16)v3;
                *reinterpret_cast<f16x4*>(dst0 + mt*16) = o;
            }
        }
    }
}

// Fused offmod: all three branches in one launch (K=7 first for backfill).
__global__ __launch_bounds__(256) void offmod_all_k(
    const u16x8* __restrict__ hp8,
    const f16x8* __restrict__ wbg7, const f16x8* __restrict__ wbg5,
    const f16x8* __restrict__ wbg3,
    const float* __restrict__ boff7, const float* __restrict__ bmod7,
    const float* __restrict__ boff5, const float* __restrict__ bmod5,
    const float* __restrict__ boff3, const float* __restrict__ bmod3,
    _Float16* __restrict__ om7, _Float16* __restrict__ om5,
    _Float16* __restrict__ om3)
{
    __shared__ __align__(16) char smem[20480];
    constexpr size_t HPB = (size_t)BB*8*PLANE;
    constexpr int G7 = BB*(HW/128)*2;   // 1152
    constexpr int G5 = BB*(HW/64);      // 1152
    int blk = blockIdx.x;
    if (blk < G7)
        offmod_dev<7,2,2,2>(smem, blk, hp8, wbg7, boff7, bmod7, om7);
    else if (blk < G7 + G5)
        offmod_dev<5,1,1,2>(smem, blk - G7, hp8 + HPB, wbg5, boff5, bmod5, om5);
    else
        offmod_dev<3,2,1,3>(smem, blk - G7 - G5, hp8 + 2*HPB, wbg3, boff3, bmod3, om3);
}

// ---------------------------------------------------------------------------
// Deformable sampling + MFMA channel matmul (r20/r23 winner) as device
// function with carved LDS. Window layout [grp][ry][rx] (no XOR — r24's
// swizzle was measured neutral-negative). raw in [0, BB*NSB).
// ---------------------------------------------------------------------------
template<int K> struct DfmLds {
    static constexpr int HWW = K + 2;
    static constexpr int WWW = 16 + K + 2;
    static constexpr int WIN_B = 8*HWW*WWW*16;
    static constexpr int NPT = K*K*16;
    static constexpr int COORD_B = NPT*8 + NPT*4 + ((NPT*2 + 15)/16)*16;
    static constexpr int RED_B = 2*64*16*4;
    static constexpr int UNION_B = (COORD_B > RED_B ? COORD_B : RED_B);
    static constexpr int TOTAL = WIN_B + UNION_B;
};

template<int K>
__device__ __forceinline__ void deform_dev(
    char* smem_raw, int raw,
    const u16x8* __restrict__ hp8,
    const _Float16* __restrict__ om,
    const f16x8* __restrict__ wtb,
    _Float16* __restrict__ out)
{
    constexpr int PAD = K/2;
    constexpr int KK  = K*K;
    constexpr int NSB = HW/16;
    constexpr int HWW = K + 2;
    constexpr int WWW = 16 + K + 2;
    constexpr int WELEMS = 8*HWW*WWW;
    constexpr int NPT = KK*16;

    u16x8* win = (u16x8*)smem_raw;                    // [8][HWW][WWW] flat
    char*  ubuf = smem_raw + WELEMS*16;

    f16x4*          hco  = (f16x4*)ubuf;
    unsigned*       gofs = (unsigned*)(ubuf + NPT*8);
    unsigned short* wofs = (unsigned short*)(ubuf + NPT*8 + NPT*4);

    int swz = (raw & 7)*((BB*NSB) >> 3) + (raw >> 3);
    int b = swz / NSB, strip = swz - b*NSB;

    int tid  = threadIdx.x;
    int wave = tid >> 6;
    int l    = tid & 63;
    int lg   = l >> 4;
    int lr   = l & 15;
    int th   = wave & 1;
    int kkh  = wave >> 1;
    int pxbase = strip*16;
    int y    = pxbase / WW;               // uniform: 192 % 16 == 0
    int xs   = pxbase - y*WW;

    int wy0 = y  + HALO - PAD - 1;
    int wx0 = xs + HALO - PAD - 1;

    // ---- stage window (all 8 channel-groups, clamped) ----
    {
        const u16x8* hbb = hp8 + (size_t)(b*8)*PLANE;
        for (int idx = tid; idx < WELEMS; idx += 256) {
            int g  = idx / (HWW*WWW);
            int r2 = idx - g*(HWW*WWW);
            int r  = r2 / WWW;
            int c2 = r2 - r*WWW;
            int gy = min(max(wy0 + r, 0), HP-1);
            int gx = min(max(wx0 + c2, 0), WP-1);
            win[idx] = hbb[(size_t)g*PLANE + gy*WP + gx];
        }
    }
    // ---- precompute coords for all (px, tap) pairs ----
    {
        const _Float16* ob = om + (size_t)b*3*KK*HW + pxbase;
        for (int idx = tid; idx < NPT; idx += 256) {
            int pxl = idx & 15, t = idx >> 4;
            float offy = (float)ob[(size_t)(2*t  )*HW + pxl];
            float offx = (float)ob[(size_t)(2*t+1)*HW + pxl];
            float mk   = (float)ob[(size_t)(2*KK+t)*HW + pxl];
            int i = t / K, j = t - (t/K)*K;
            float py  = (float)(y - PAD + i) + offy;
            float pxf = (float)(xs + pxl - PAD + j) + offx;
            float fy = floorf(py), fx = floorf(pxf);
            float wy1 = py - fy, wx1 = pxf - fx;
            int iy0 = (int)fy, ix0 = (int)fx;
            int Y0 = min(max(iy0, -1), HH) + HALO;   // zero-halo clamp
            int X0 = min(max(ix0, -1), WW) + HALO;
            int ry = Y0 - wy0, rx = X0 - wx0;
            bool in = ((unsigned)ry <= (unsigned)(HWW-2)) &
                      ((unsigned)rx <= (unsigned)(WWW-2));
            f16x4 h;
            h[0] = (_Float16)((1.f-wy1)*(1.f-wx1)*mk);
            h[1] = (_Float16)((1.f-wy1)*wx1*mk);
            h[2] = (_Float16)(wy1*(1.f-wx1)*mk);
            h[3] = (_Float16)(wy1*wx1*mk);
            hco[idx]  = h;
            gofs[idx] = (unsigned)(Y0*WP + X0);
            wofs[idx] = (unsigned short)((ry*WWW + rx) | (in ? 0 : 0x8000));
        }
    }
    __syncthreads();

    int t0 = (KK*th)/2, t1 = (KK*(th+1))/2;

    f32x4 acc[4];
    #pragma unroll
    for (int ot = 0; ot < 4; ot++) acc[ot] = (f32x4)0.f;

    const u16x8* hb   = hp8 + (size_t)(b*8 + kkh*4 + lg)*PLANE;
    const u16x8* wing = win + (kkh*4 + lg)*(HWW*WWW);

    #pragma unroll 1
    for (int t = t0; t < t1; t++) {
        int idx = t*16 + lr;
        f16x4 h = hco[idx];
        unsigned short wf = wofs[idx];
        bool in = (wf & 0x8000) == 0;

        f16x8 c0, c1, c2, c3;
        if (__all(in)) {
            const u16x8* Wp = wing + wf;
            c0 = bc16(Wp[0]);   c1 = bc16(Wp[1]);
            c2 = bc16(Wp[WWW]); c3 = bc16(Wp[WWW+1]);
        } else {
            const u16x8* G = hb + gofs[idx];
            c0 = bc16(G[0]);  c1 = bc16(G[1]);
            c2 = bc16(G[WP]); c3 = bc16(G[WP+1]);
        }

        f16x8 s = c0*h[0] + c1*h[1] + c2*h[2] + c3*h[3];

        const f16x8* bp = wtb + (size_t)t*8*64 + l;
        #pragma unroll
        for (int ot = 0; ot < 4; ot++) {
            acc[ot] = __builtin_amdgcn_mfma_f32_16x16x32_f16(
                s, bp[(size_t)(kkh*4 + ot)*64], acc[ot], 0, 0, 0);
        }
    }

    // ---- two-stage reduce, XOR-swizzled (ubuf reused) ----
    __syncthreads();
    float* redf = (float*)ubuf;   // logical [2][64][16] f32, swizzled px dim
    #define RIDX(tt, o, g)  (((tt)*64 + (o))*16 + (((g) ^ ((o) & 3)) * 4))
    if (kkh == 1) {
        #pragma unroll
        for (int ot = 0; ot < 4; ot++) {
            int o = ot*16 + lr;
            *reinterpret_cast<f32x4*>(&redf[RIDX(th, o, lg)]) = acc[ot];
        }
    }
    __syncthreads();
    if (kkh == 0) {
        #pragma unroll
        for (int ot = 0; ot < 4; ot++) {
            int o = ot*16 + lr;
            acc[ot] += *reinterpret_cast<const f32x4*>(&redf[RIDX(th, o, lg)]);
        }
    }
    __syncthreads();
    if (kkh == 0 && th == 1) {
        #pragma unroll
        for (int ot = 0; ot < 4; ot++) {
            int o = ot*16 + lr;
            *reinterpret_cast<f32x4*>(&redf[RIDX(0, o, lg)]) = acc[ot];
        }
    }
    __syncthreads();
    if (kkh == 0 && th == 0) {
        _Float16* ob = out + (size_t)b*CC*HW + pxbase + lg*4;
        #pragma unroll
        for (int ot = 0; ot < 4; ot++) {
            int o = ot*16 + lr;
            f32x4 rr = *reinterpret_cast<const f32x4*>(&redf[RIDX(0, o, lg)]);
            rr += acc[ot];
            f16x4 v;
            v[0] = (_Float16)rr[0]; v[1] = (_Float16)rr[1];
            v[2] = (_Float16)rr[2]; v[3] = (_Float16)rr[3];
            *reinterpret_cast<f16x4*>(ob + (size_t)o*HW) = v;
        }
    }
    #undef RIDX
}

// Fused deform: all three branches in one launch (K=7 first).
__global__ __launch_bounds__(256, 4) void deform_all_k(
    const u16x8* __restrict__ hp8,
    const _Float16* __restrict__ om7, const _Float16* __restrict__ om5,
    const _Float16* __restrict__ om3,
    const f16x8* __restrict__ wtb7, const f16x8* __restrict__ wtb5,
    const f16x8* __restrict__ wtb3,
    _Float16* __restrict__ aa, _Float16* __restrict__ mm,
    _Float16* __restrict__ sm)
{
    constexpr int DFM_SMEM =
        (DfmLds<7>::TOTAL > DfmLds<5>::TOTAL ?
            (DfmLds<7>::TOTAL > DfmLds<3>::TOTAL ? DfmLds<7>::TOTAL : DfmLds<3>::TOTAL)
          : (DfmLds<5>::TOTAL > DfmLds<3>::TOTAL ? DfmLds<5>::TOTAL : DfmLds<3>::TOTAL));
    __shared__ __align__(16) char smem[DFM_SMEM];
    constexpr size_t HPB = (size_t)BB*8*PLANE;
    constexpr int GD = BB*(HW/16);     // 4608 per branch
    int blk = blockIdx.x;
    if (blk < GD)
        deform_dev<7>(smem, blk, hp8, om7, wtb7, aa);
    else if (blk < 2*GD)
        deform_dev<5>(smem, blk - GD, hp8 + HPB, om5, wtb5, mm);
    else
        deform_dev<3>(smem, blk - 2*GD, hp8 + 2*HPB, om3, wtb3, sm);
}

// ---------------------------------------------------------------------------
// Launch. Workspace (bytes):
//   hp8 x3 : 3 * BB*8*PLANE*16B = ~30.1 MB
//   om7/om5/om3 : 21.7 / 11.1 / 4.0 MB (f16)  [u aliases om7 after deforms]
//   aa/mm/sm : BB*CC*HW*2B each = ~9.4 MB each (f16)
//   weights : ~2.0 MB      total ~97.2 MB
// 6 launches total.
// ---------------------------------------------------------------------------
extern "C" void kernel_launch(void* const* d_in, const int* in_sizes, int n_in,
                              void* d_out, int out_size, void* d_ws, size_t ws_size,
                              hipStream_t stream)
{
    const float* x_max      = (const float*)d_in[0];
    const float* x_mid      = (const float*)d_in[1];
    const float* x_small    = (const float*)d_in[2];
    const float* w_pre_max  = (const float*)d_in[3];
    const float* w_off_max  = (const float*)d_in[4];
    const float* b_off_max  = (const float*)d_in[5];
    const float* w_mod_max  = (const float*)d_in[6];
    const float* b_mod_max  = (const float*)d_in[7];
    const float* w_reg_max  = (const float*)d_in[8];
    const float* w_pre_mid  = (const float*)d_in[9];
    const float* w_off_mid  = (const float*)d_in[10];
    const float* b_off_mid  = (const float*)d_in[11];
    const float* w_mod_mid  = (const float*)d_in[12];
    const float* b_mod_mid  = (const float*)d_in[13];
    const float* w_reg_mid  = (const float*)d_in[14];
    const float* w_pre_small= (const float*)d_in[15];
    const float* w_off_small= (const float*)d_in[16];
    const float* b_off_small= (const float*)d_in[17];
    const float* w_mod_small= (const float*)d_in[18];
    const float* b_mod_small= (const float*)d_in[19];
    const float* w_reg_small= (const float*)d_in[20];
    const float* w1         = (const float*)d_in[21];
    const float* w2         = (const float*)d_in[22];

    float* out = (float*)d_out;
    char*  ws  = (char*)d_ws;

    const size_t HPB = (size_t)BB*8*PLANE;      // u16x8 elems per branch

    u16x8*    hp8 = (u16x8*)ws;                 ws += 3*HPB*16;
    _Float16* om7 = (_Float16*)ws;              ws += (size_t)BB*3*49*HW*2;
    _Float16* om5 = (_Float16*)ws;              ws += (size_t)BB*3*25*HW*2;
    _Float16* om3 = (_Float16*)ws;              ws += (size_t)BB*3*9*HW*2;
    _Float16* aa  = (_Float16*)ws;              ws += (size_t)BB*CC*HW*2;
    _Float16* mm  = (_Float16*)ws;              ws += (size_t)BB*CC*HW*2;
    _Float16* sm  = (_Float16*)ws;              ws += (size_t)BB*CC*HW*2;
    f16x8*    wtb7= (f16x8*)ws;                 ws += (size_t)49*512*16;
    f16x8*    wbg7= (f16x8*)ws;                 ws += (size_t)49*2*10*64*16;
    f16x8*    wtb5= (f16x8*)ws;                 ws += (size_t)25*512*16;
    f16x8*    wbg5= (f16x8*)ws;                 ws += (size_t)25*2*5*64*16;
    f16x8*    wtb3= (f16x8*)ws;                 ws += (size_t)9*512*16;
    f16x8*    wbg3= (f16x8*)ws;
    _Float16* u   = om7;   // om7 dead after deform_all_k

    hipMemsetAsync(hp8, 0, 3*HPB*16, stream);

    const int npix_blocks = (BB*HW)/256;       // 288
    const int off_blocks  = BB*(HW/128)*2 + BB*(HW/64) + BB*(HW/128); // 2880
    const int dfm_blocks  = 3*BB*(HW/16);      // 13824

    bake_all_k<<<83, 256, 0, stream>>>(
        w_reg_max, w_off_max, w_mod_max,
        w_reg_mid, w_off_mid, w_mod_mid,
        w_reg_small, w_off_small, w_mod_small,
        wtb7, wbg7, wtb5, wbg5, wtb3, wbg3);
    conv_pre_k<<<dim3(npix_blocks, 2, 3), 256, 0, stream>>>(
        x_max, x_mid, x_small, w_pre_max, w_pre_mid, w_pre_small, hp8);

    offmod_all_k<<<off_blocks, 256, 0, stream>>>(
        hp8, wbg7, wbg5, wbg3,
        b_off_max, b_mod_max, b_off_mid, b_mod_mid, b_off_small, b_mod_small,
        om7, om5, om3);

    deform_all_k<<<dfm_blocks, 256, 0, stream>>>(
        hp8, om7, om5, om3, wtb7, wtb5, wtb3, aa, mm, sm);

    conv1x1_k<1><<<dim3(npix_blocks,2), 256, 0, stream>>>(aa, mm, w1,
                                                  nullptr, nullptr, nullptr, u);
    conv1x1_k<2><<<dim3(npix_blocks,2), 256, 0, stream>>>(u, sm, w2,
                                                  x_max, x_mid, x_small, out);
}

// Round 26
// 383.228 us; speedup vs baseline: 1.0395x; 1.0333x over previous
//
#include <hip/hip_runtime.h>
#include <hip/hip_bf16.h>
#include <math.h>

// Geometry (fixed by the reference)
#define BB   2
#define CC   64
#define HH   192
#define WW   192
#define HW   (HH*WW)          // 36864
#define HALO 3
#define HP   (HH + 2*HALO)    // 198
#define WP   (WW + 2*HALO)    // 198
#define PLANE (HP*WP)         // 39204

typedef __attribute__((ext_vector_type(8))) _Float16 f16x8;
typedef __attribute__((ext_vector_type(4))) _Float16 f16x4;
typedef __attribute__((ext_vector_type(8))) unsigned short u16x8;
typedef __attribute__((ext_vector_type(4))) float f32x4;

__device__ __forceinline__ float fast_tanh(float x) {
    float e = __expf(2.f * x);
    return 1.f - 2.f * __builtin_amdgcn_rcpf(e + 1.f);
}
__device__ __forceinline__ f16x8 bc16(u16x8 v) { return __builtin_bit_cast(f16x8, v); }

// ---------------------------------------------------------------------------
// Fused pre-conv: relu(Wz @ Xz) -> PADDED fp16 hp8 layout, branch z = blockIdx.z
// ---------------------------------------------------------------------------
__global__ __launch_bounds__(256) void conv_pre_k(
    const float* __restrict__ X0, const float* __restrict__ X1,
    const float* __restrict__ X2,
    const float* __restrict__ W0, const float* __restrict__ W1,
    const float* __restrict__ W2,
    u16x8* __restrict__ hp8all)
{
    __shared__ float wl[64*32];   // [c][o_half]
    int tid = threadIdx.x;
    int oh  = blockIdx.y;
    int z   = blockIdx.z;
    const float* X = (z == 0) ? X0 : ((z == 1) ? X1 : X2);
    const float* W = (z == 0) ? W0 : ((z == 1) ? W1 : W2);
    u16x8* hp8 = hp8all + (size_t)z * ((size_t)BB*8*PLANE);

    #pragma unroll
    for (int n = 0; n < 8; n++) {
        int idx = tid + n*256;
        int op  = idx >> 6, c = idx & 63;
        wl[c*32 + op] = W[(size_t)(oh*32 + op)*64 + c];
    }
    __syncthreads();

    int p  = blockIdx.x*256 + tid;
    int b  = p / HW;
    int pp = p - b*HW;
    size_t base = (size_t)b*CC*HW + pp;

    float acc[32];
    #pragma unroll
    for (int o = 0; o < 32; o++) acc[o] = 0.f;

    #pragma unroll 4
    for (int c = 0; c < 64; c++) {
        float xv = X[base + (size_t)c*HW];
        const float4* w4 = (const float4*)(wl + c*32);
        #pragma unroll
        for (int q = 0; q < 8; q++) {
            float4 w = w4[q];
            acc[4*q+0] = fmaf(w.x, xv, acc[4*q+0]);
            acc[4*q+1] = fmaf(w.y, xv, acc[4*q+1]);
            acc[4*q+2] = fmaf(w.z, xv, acc[4*q+2]);
            acc[4*q+3] = fmaf(w.w, xv, acc[4*q+3]);
        }
    }

    int y = pp / WW, x = pp - y*WW;
    #pragma unroll
    for (int gq = 0; gq < 4; gq++) {
        u16x8 v;
        #pragma unroll
        for (int c = 0; c < 8; c++)
            v[c] = __builtin_bit_cast(unsigned short,
                     (_Float16)fmaxf(acc[gq*8+c], 0.f));
        hp8[(size_t)(b*8 + oh*4 + gq)*PLANE + (size_t)(y+HALO)*WP + (x+HALO)] = v;
    }
}

// ---------------------------------------------------------------------------
// 1x1 conv combine stages (f16 in):
// MODE 1: relu(W@(X*tanh(M)))  -> flat f16
// MODE 2: relu(W@(X*tanh(M))) + Y0+Y1+Y2 -> flat f32 (d_out)
// ---------------------------------------------------------------------------
template<int MODE>
__global__ __launch_bounds__(256) void conv1x1_k(
    const _Float16* __restrict__ Xv, const _Float16* __restrict__ Mv,
    const float* __restrict__ W,
    const float* __restrict__ Y0, const float* __restrict__ Y1,
    const float* __restrict__ Y2,
    void* __restrict__ outv)
{
    __shared__ float wl[64*32];
    int tid = threadIdx.x;
    int oh  = blockIdx.y;
    #pragma unroll
    for (int n = 0; n < 8; n++) {
        int idx = tid + n*256;
        int op  = idx >> 6, c = idx & 63;
        wl[c*32 + op] = W[(size_t)(oh*32 + op)*64 + c];
    }
    __syncthreads();

    int p  = blockIdx.x*256 + tid;
    int b  = p / HW;
    int pp = p - b*HW;
    size_t base = (size_t)b*CC*HW + pp;

    float acc[32];
    #pragma unroll
    for (int o = 0; o < 32; o++) acc[o] = 0.f;

    #pragma unroll 4
    for (int c = 0; c < 64; c++) {
        float xv = (float)Xv[base + (size_t)c*HW];
        xv *= fast_tanh((float)Mv[base + (size_t)c*HW]);
        const float4* w4 = (const float4*)(wl + c*32);
        #pragma unroll
        for (int q = 0; q < 8; q++) {
            float4 w = w4[q];
            acc[4*q+0] = fmaf(w.x, xv, acc[4*q+0]);
            acc[4*q+1] = fmaf(w.y, xv, acc[4*q+1]);
            acc[4*q+2] = fmaf(w.z, xv, acc[4*q+2]);
            acc[4*q+3] = fmaf(w.w, xv, acc[4*q+3]);
        }
    }

    if (MODE == 1) {
        _Float16* op = (_Float16*)outv + base + (size_t)(oh*32)*HW;
        #pragma unroll
        for (int o = 0; o < 32; o++)
            op[(size_t)o*HW] = (_Float16)fmaxf(acc[o], 0.f);
    } else {
        float* op = (float*)outv + base + (size_t)(oh*32)*HW;
        size_t gi = base + (size_t)(oh*32)*HW;
        #pragma unroll
        for (int o = 0; o < 32; o++) {
            float yv = Y0[gi + (size_t)o*HW] + Y1[gi + (size_t)o*HW] + Y2[gi + (size_t)o*HW];
            op[(size_t)o*HW] = fmaxf(acc[o], 0.f) + yv;
        }
    }
}

// ---------------------------------------------------------------------------
// Weight baking (device helpers + single fused kernel, 83 blocks).
// ---------------------------------------------------------------------------
template<int K>
__device__ void bake_wtb_dev(const float* __restrict__ Wreg,
                             f16x8* __restrict__ wtb, int t, int tid)
{
    constexpr int KK = K*K;
    for (int e = tid; e < 512; e += 256) {
        int kk = e >> 8, rem = e & 255;
        int ot = rem >> 6, l = rem & 63;
        int lr = l & 15, lg = l >> 4;
        int o  = ot*16 + lr;
        f16x8 v;
        #pragma unroll
        for (int j = 0; j < 8; j++) {
            int c = kk*32 + lg*8 + j;
            v[j] = (_Float16)Wreg[((size_t)o*CC + c)*KK + t];
        }
        wtb[(size_t)t*512 + e] = v;
    }
}
template<int K>
__device__ void bake_wbg_dev(const float* __restrict__ Woff,
                             const float* __restrict__ Wmod,
                             f16x8* __restrict__ wbg, int pos, int tid)
{
    constexpr int KK  = K*K;
    constexpr int NTF = (3*KK + 15)/16;
    for (int idx = tid; idx < 2*NTF*64; idx += 256) {
        int kk  = idx / (NTF*64);
        int rem = idx - kk*(NTF*64);
        int nt  = rem >> 6;
        int l   = rem & 63;
        int lg  = l >> 4, lr = l & 15;
        int n   = nt*16 + lr;
        f16x8 v;
        #pragma unroll
        for (int j = 0; j < 8; j++) {
            int c = kk*32 + lg*8 + j;
            float w = 0.f;
            if (n < 2*KK)      w = Woff[((size_t)n*CC + c)*KK + pos];
            else if (n < 3*KK) w = Wmod[((size_t)(n - 2*KK)*CC + c)*KK + pos];
            v[j] = (_Float16)w;
        }
        wbg[(size_t)pos*(2*NTF*64) + idx] = v;
    }
}
__global__ __launch_bounds__(256) void bake_all_k(
    const float* wreg7, const float* woff7, const float* wmod7,
    const float* wreg5, const float* woff5, const float* wmod5,
    const float* wreg3, const float* woff3, const float* wmod3,
    f16x8* wtb7, f16x8* wbg7, f16x8* wtb5, f16x8* wbg5,
    f16x8* wtb3, f16x8* wbg3)
{
    int blk = blockIdx.x, tid = threadIdx.x;
    if (blk < 49) {
        bake_wtb_dev<7>(wreg7, wtb7, blk, tid);
        bake_wbg_dev<7>(woff7, wmod7, wbg7, blk, tid);
    } else if (blk < 74) {
        int p = blk - 49;
        bake_wtb_dev<5>(wreg5, wtb5, p, tid);
        bake_wbg_dev<5>(woff5, wmod5, wbg5, p, tid);
    } else {
        int p = blk - 74;
        bake_wtb_dev<3>(wreg3, wtb3, p, tid);
        bake_wbg_dev<3>(woff3, wmod3, wbg3, p, tid);
    }
}

// ---------------------------------------------------------------------------
// Offset + mask KxK conv (PPR-staged LDS B). r26: MT raised (2->4 for K=7,
// 1->2 for K=5, 2->4 for K=3) — twice the MFMA per barrier round amortizes
// the per-round {barrier + A-load latency} stall; block count halves.
// raw in [0, NBLK).
// ---------------------------------------------------------------------------
template<int K, int MT, int NS, int PPR>
__device__ __forceinline__ void offmod_dev(
    char* smem_raw, int raw,
    const u16x8* __restrict__ hp8,
    const f16x8* __restrict__ wbg,
    const float* __restrict__ Boff, const float* __restrict__ Bmod,
    _Float16* __restrict__ om)
{
    constexpr int PAD  = K/2;
    constexpr int KK   = K*K;
    constexpr int NTF  = (3*KK + 15)/16;
    constexpr int NT   = NTF/NS;
    constexpr int PBB  = HW/(64*MT);
    constexpr int NBLK = BB*PBB*NS;
    constexpr int ROUNDS = (KK + PPR - 1)/PPR;
    constexpr int WELEM  = PPR*2*NT*64;

    f16x8* wl = (f16x8*)smem_raw;

    int swz = (raw & 7)*(NBLK >> 3) + (raw >> 3);
    int ng  = swz % NS;
    int s   = swz / NS;
    int b   = s / PBB;
    int blk = s - b*PBB;

    int tid  = threadIdx.x;
    int wave = tid >> 6;
    int l    = tid & 63;
    int lg   = l >> 4, lr = l & 15;
    int pxw  = blk*(4*MT*16) + wave*(MT*16);
    int y    = pxw / WW, x0 = pxw - y*WW;

    f32x4 acc[MT][NT];
    #pragma unroll
    for (int mt = 0; mt < MT; mt++)
        #pragma unroll
        for (int nt = 0; nt < NT; nt++) acc[mt][nt] = (f32x4)0.f;

    const u16x8* hb = hp8 + (size_t)(b*8)*PLANE;

    for (int r = 0; r < ROUNDS; r++) {
        __syncthreads();
        #pragma unroll
        for (int ii = 0; ii < (WELEM + 255)/256; ii++) {
            int idx = tid + ii*256;
            if (WELEM % 256 == 0 || idx < WELEM) {
                int pp  = idx / (2*NT*64);
                int rem = idx - pp*(2*NT*64);
                int kk  = rem / (NT*64);
                int rem2= rem - kk*(NT*64);
                int nt  = rem2 >> 6;
                int ll  = rem2 & 63;
                int pos = r*PPR + pp;
                if (pos < KK)
                    wl[idx] = wbg[(size_t)pos*(2*NTF*64)
                                  + (size_t)(kk*NTF + ng*NT + nt)*64 + ll];
            }
        }
        __syncthreads();

        #pragma unroll
        for (int pp = 0; pp < PPR; pp++) {
            int pos = r*PPR + pp;
            if (pos >= KK) break;
            int i = pos / K, j = pos - (pos/K)*K;
            int rbase = (y + HALO - PAD + i)*WP + (x0 + HALO - PAD + j);

            #pragma unroll
            for (int kk = 0; kk < 2; kk++) {
                const f16x8* G = (const f16x8*)(hb + (size_t)(kk*4 + lg)*PLANE + rbase);
                f16x8 a[MT];
                #pragma unroll
                for (int mt = 0; mt < MT; mt++) a[mt] = G[mt*16 + lr];
                #pragma unroll
                for (int nt = 0; nt < NT; nt++) {
                    f16x8 bf = wl[((pp*2 + kk)*NT + nt)*64 + l];
                    #pragma unroll
                    for (int mt = 0; mt < MT; mt++)
                        acc[mt][nt] = __builtin_amdgcn_mfma_f32_16x16x32_f16(
                            a[mt], bf, acc[mt][nt], 0, 0, 0);
                }
            }
        }
    }

    #pragma unroll
    for (int nt = 0; nt < NT; nt++) {
        int n = ng*NT*16 + nt*16 + lr;
        if (n < 3*KK) {
            bool is_mask = (n >= 2*KK);
            float bias = is_mask ? Bmod[n - 2*KK] : Boff[n];
            _Float16* dst0 = om + ((size_t)b*3*KK + n)*HW + pxw + lg*4;
            #pragma unroll
            for (int mt = 0; mt < MT; mt++) {
                f32x4 v = acc[mt][nt];
                float v0 = v[0] + bias, v1 = v[1] + bias, v2 = v[2] + bias, v3 = v[3] + bias;
                if (is_mask) {
                    v0 = 2.f * __builtin_amdgcn_rcpf(1.f + __expf(-v0));
                    v1 = 2.f * __builtin_amdgcn_rcpf(1.f + __expf(-v1));
                    v2 = 2.f * __builtin_amdgcn_rcpf(1.f + __expf(-v2));
                    v3 = 2.f * __builtin_amdgcn_rcpf(1.f + __expf(-v3));
                }
                f16x4 o;
                o[0] = (_Float16)v0; o[1] = (_Float16)v1;
                o[2] = (_Float16)v2; o[3] = (_Float16)v3;
                *reinterpret_cast<f16x4*>(dst0 + mt*16) = o;
            }
        }
    }
}

// Fused offmod: all three branches in one launch (K=7 first for backfill).
// r26 grids: K7 MT=4 -> 576, K5 MT=2 -> 576, K3 MT=4 -> 288; total 1440.
__global__ __launch_bounds__(256) void offmod_all_k(
    const u16x8* __restrict__ hp8,
    const f16x8* __restrict__ wbg7, const f16x8* __restrict__ wbg5,
    const f16x8* __restrict__ wbg3,
    const float* __restrict__ boff7, const float* __restrict__ bmod7,
    const float* __restrict__ boff5, const float* __restrict__ bmod5,
    const float* __restrict__ boff3, const float* __restrict__ bmod3,
    _Float16* __restrict__ om7, _Float16* __restrict__ om5,
    _Float16* __restrict__ om3)
{
    __shared__ __align__(16) char smem[20480];
    constexpr size_t HPB = (size_t)BB*8*PLANE;
    constexpr int G7 = BB*(HW/256)*2;   // MT=4, NS=2 -> 576
    constexpr int G5 = BB*(HW/128);     // MT=2, NS=1 -> 576
    int blk = blockIdx.x;
    if (blk < G7)
        offmod_dev<7,4,2,2>(smem, blk, hp8, wbg7, boff7, bmod7, om7);
    else if (blk < G7 + G5)
        offmod_dev<5,2,1,2>(smem, blk - G7, hp8 + HPB, wbg5, boff5, bmod5, om5);
    else
        offmod_dev<3,4,1,3>(smem, blk - G7 - G5, hp8 + 2*HPB, wbg3, boff3, bmod3, om3);
}

// ---------------------------------------------------------------------------
// Deformable sampling + MFMA channel matmul (r23 winner, unchanged).
// ---------------------------------------------------------------------------
template<int K> struct DfmLds {
    static constexpr int HWW = K + 2;
    static constexpr int WWW = 16 + K + 2;
    static constexpr int WIN_B = 8*HWW*WWW*16;
    static constexpr int NPT = K*K*16;
    static constexpr int COORD_B = NPT*8 + NPT*4 + ((NPT*2 + 15)/16)*16;
    static constexpr int RED_B = 2*64*16*4;
    static constexpr int UNION_B = (COORD_B > RED_B ? COORD_B : RED_B);
    static constexpr int TOTAL = WIN_B + UNION_B;
};

template<int K>
__device__ __forceinline__ void deform_dev(
    char* smem_raw, int raw,
    const u16x8* __restrict__ hp8,
    const _Float16* __restrict__ om,
    const f16x8* __restrict__ wtb,
    _Float16* __restrict__ out)
{
    constexpr int PAD = K/2;
    constexpr int KK  = K*K;
    constexpr int NSB = HW/16;
    constexpr int HWW = K + 2;
    constexpr int WWW = 16 + K + 2;
    constexpr int WELEMS = 8*HWW*WWW;
    constexpr int NPT = KK*16;

    u16x8* win = (u16x8*)smem_raw;                    // [8][HWW][WWW] flat
    char*  ubuf = smem_raw + WELEMS*16;

    f16x4*          hco  = (f16x4*)ubuf;
    unsigned*       gofs = (unsigned*)(ubuf + NPT*8);
    unsigned short* wofs = (unsigned short*)(ubuf + NPT*8 + NPT*4);

    int swz = (raw & 7)*((BB*NSB) >> 3) + (raw >> 3);
    int b = swz / NSB, strip = swz - b*NSB;

    int tid  = threadIdx.x;
    int wave = tid >> 6;
    int l    = tid & 63;
    int lg   = l >> 4;
    int lr   = l & 15;
    int th   = wave & 1;
    int kkh  = wave >> 1;
    int pxbase = strip*16;
    int y    = pxbase / WW;               // uniform: 192 % 16 == 0
    int xs   = pxbase - y*WW;

    int wy0 = y  + HALO - PAD - 1;
    int wx0 = xs + HALO - PAD - 1;

    // ---- stage window (all 8 channel-groups, clamped) ----
    {
        const u16x8* hbb = hp8 + (size_t)(b*8)*PLANE;
        for (int idx = tid; idx < WELEMS; idx += 256) {
            int g  = idx / (HWW*WWW);
            int r2 = idx - g*(HWW*WWW);
            int r  = r2 / WWW;
            int c2 = r2 - r*WWW;
            int gy = min(max(wy0 + r, 0), HP-1);
            int gx = min(max(wx0 + c2, 0), WP-1);
            win[idx] = hbb[(size_t)g*PLANE + gy*WP + gx];
        }
    }
    // ---- precompute coords for all (px, tap) pairs ----
    {
        const _Float16* ob = om + (size_t)b*3*KK*HW + pxbase;
        for (int idx = tid; idx < NPT; idx += 256) {
            int pxl = idx & 15, t = idx >> 4;
            float offy = (float)ob[(size_t)(2*t  )*HW + pxl];
            float offx = (float)ob[(size_t)(2*t+1)*HW + pxl];
            float mk   = (float)ob[(size_t)(2*KK+t)*HW + pxl];
            int i = t / K, j = t - (t/K)*K;
            float py  = (float)(y - PAD + i) + offy;
            float pxf = (float)(xs + pxl - PAD + j) + offx;
            float fy = floorf(py), fx = floorf(pxf);
            float wy1 = py - fy, wx1 = pxf - fx;
            int iy0 = (int)fy, ix0 = (int)fx;
            int Y0 = min(max(iy0, -1), HH) + HALO;   // zero-halo clamp
            int X0 = min(max(ix0, -1), WW) + HALO;
            int ry = Y0 - wy0, rx = X0 - wx0;
            bool in = ((unsigned)ry <= (unsigned)(HWW-2)) &
                      ((unsigned)rx <= (unsigned)(WWW-2));
            f16x4 h;
            h[0] = (_Float16)((1.f-wy1)*(1.f-wx1)*mk);
            h[1] = (_Float16)((1.f-wy1)*wx1*mk);
            h[2] = (_Float16)(wy1*(1.f-wx1)*mk);
            h[3] = (_Float16)(wy1*wx1*mk);
            hco[idx]  = h;
            gofs[idx] = (unsigned)(Y0*WP + X0);
            wofs[idx] = (unsigned short)((ry*WWW + rx) | (in ? 0 : 0x8000));
        }
    }
    __syncthreads();

    int t0 = (KK*th)/2, t1 = (KK*(th+1))/2;

    f32x4 acc[4];
    #pragma unroll
    for (int ot = 0; ot < 4; ot++) acc[ot] = (f32x4)0.f;

    const u16x8* hb   = hp8 + (size_t)(b*8 + kkh*4 + lg)*PLANE;
    const u16x8* wing = win + (kkh*4 + lg)*(HWW*WWW);

    #pragma unroll 1
    for (int t = t0; t < t1; t++) {
        int idx = t*16 + lr;
        f16x4 h = hco[idx];
        unsigned short wf = wofs[idx];
        bool in = (wf & 0x8000) == 0;

        f16x8 c0, c1, c2, c3;
        if (__all(in)) {
            const u16x8* Wp = wing + wf;
            c0 = bc16(Wp[0]);   c1 = bc16(Wp[1]);
            c2 = bc16(Wp[WWW]); c3 = bc16(Wp[WWW+1]);
        } else {
            const u16x8* G = hb + gofs[idx];
            c0 = bc16(G[0]);  c1 = bc16(G[1]);
            c2 = bc16(G[WP]); c3 = bc16(G[WP+1]);
        }

        f16x8 s = c0*h[0] + c1*h[1] + c2*h[2] + c3*h[3];

        const f16x8* bp = wtb + (size_t)t*8*64 + l;
        #pragma unroll
        for (int ot = 0; ot < 4; ot++) {
            acc[ot] = __builtin_amdgcn_mfma_f32_16x16x32_f16(
                s, bp[(size_t)(kkh*4 + ot)*64], acc[ot], 0, 0, 0);
        }
    }

    // ---- two-stage reduce, XOR-swizzled (ubuf reused) ----
    __syncthreads();
    float* redf = (float*)ubuf;   // logical [2][64][16] f32, swizzled px dim
    #define RIDX(tt, o, g)  (((tt)*64 + (o))*16 + (((g) ^ ((o) & 3)) * 4))
    if (kkh == 1) {
        #pragma unroll
        for (int ot = 0; ot < 4; ot++) {
            int o = ot*16 + lr;
            *reinterpret_cast<f32x4*>(&redf[RIDX(th, o, lg)]) = acc[ot];
        }
    }
    __syncthreads();
    if (kkh == 0) {
        #pragma unroll
        for (int ot = 0; ot < 4; ot++) {
            int o = ot*16 + lr;
            acc[ot] += *reinterpret_cast<const f32x4*>(&redf[RIDX(th, o, lg)]);
        }
    }
    __syncthreads();
    if (kkh == 0 && th == 1) {
        #pragma unroll
        for (int ot = 0; ot < 4; ot++) {
            int o = ot*16 + lr;
            *reinterpret_cast<f32x4*>(&redf[RIDX(0, o, lg)]) = acc[ot];
        }
    }
    __syncthreads();
    if (kkh == 0 && th == 0) {
        _Float16* ob = out + (size_t)b*CC*HW + pxbase + lg*4;
        #pragma unroll
        for (int ot = 0; ot < 4; ot++) {
            int o = ot*16 + lr;
            f32x4 rr = *reinterpret_cast<const f32x4*>(&redf[RIDX(0, o, lg)]);
            rr += acc[ot];
            f16x4 v;
            v[0] = (_Float16)rr[0]; v[1] = (_Float16)rr[1];
            v[2] = (_Float16)rr[2]; v[3] = (_Float16)rr[3];
            *reinterpret_cast<f16x4*>(ob + (size_t)o*HW) = v;
        }
    }
    #undef RIDX
}

// Fused deform: all three branches in one launch (K=7 first).
__global__ __launch_bounds__(256, 4) void deform_all_k(
    const u16x8* __restrict__ hp8,
    const _Float16* __restrict__ om7, const _Float16* __restrict__ om5,
    const _Float16* __restrict__ om3,
    const f16x8* __restrict__ wtb7, const f16x8* __restrict__ wtb5,
    const f16x8* __restrict__ wtb3,
    _Float16* __restrict__ aa, _Float16* __restrict__ mm,
    _Float16* __restrict__ sm)
{
    constexpr int DFM_SMEM =
        (DfmLds<7>::TOTAL > DfmLds<5>::TOTAL ?
            (DfmLds<7>::TOTAL > DfmLds<3>::TOTAL ? DfmLds<7>::TOTAL : DfmLds<3>::TOTAL)
          : (DfmLds<5>::TOTAL > DfmLds<3>::TOTAL ? DfmLds<5>::TOTAL : DfmLds<3>::TOTAL));
    __shared__ __align__(16) char smem[DFM_SMEM];
    constexpr size_t HPB = (size_t)BB*8*PLANE;
    constexpr int GD = BB*(HW/16);     // 4608 per branch
    int blk = blockIdx.x;
    if (blk < GD)
        deform_dev<7>(smem, blk, hp8, om7, wtb7, aa);
    else if (blk < 2*GD)
        deform_dev<5>(smem, blk - GD, hp8 + HPB, om5, wtb5, mm);
    else
        deform_dev<3>(smem, blk - 2*GD, hp8 + 2*HPB, om3, wtb3, sm);
}

// ---------------------------------------------------------------------------
// Launch. Workspace (bytes):
//   hp8 x3 : 3 * BB*8*PLANE*16B = ~30.1 MB
//   om7/om5/om3 : 21.7 / 11.1 / 4.0 MB (f16)  [u aliases om7 after deforms]
//   aa/mm/sm : BB*CC*HW*2B each = ~9.4 MB each (f16)
//   weights : ~2.0 MB      total ~97.2 MB
// 6 launches total.
// ---------------------------------------------------------------------------
extern "C" void kernel_launch(void* const* d_in, const int* in_sizes, int n_in,
                              void* d_out, int out_size, void* d_ws, size_t ws_size,
                              hipStream_t stream)
{
    const float* x_max      = (const float*)d_in[0];
    const float* x_mid      = (const float*)d_in[1];
    const float* x_small    = (const float*)d_in[2];
    const float* w_pre_max  = (const float*)d_in[3];
    const float* w_off_max  = (const float*)d_in[4];
    const float* b_off_max  = (const float*)d_in[5];
    const float* w_mod_max  = (const float*)d_in[6];
    const float* b_mod_max  = (const float*)d_in[7];
    const float* w_reg_max  = (const float*)d_in[8];
    const float* w_pre_mid  = (const float*)d_in[9];
    const float* w_off_mid  = (const float*)d_in[10];
    const float* b_off_mid  = (const float*)d_in[11];
    const float* w_mod_mid  = (const float*)d_in[12];
    const float* b_mod_mid  = (const float*)d_in[13];
    const float* w_reg_mid  = (const float*)d_in[14];
    const float* w_pre_small= (const float*)d_in[15];
    const float* w_off_small= (const float*)d_in[16];
    const float* b_off_small= (const float*)d_in[17];
    const float* w_mod_small= (const float*)d_in[18];
    const float* b_mod_small= (const float*)d_in[19];
    const float* w_reg_small= (const float*)d_in[20];
    const float* w1         = (const float*)d_in[21];
    const float* w2         = (const float*)d_in[22];

    float* out = (float*)d_out;
    char*  ws  = (char*)d_ws;

    const size_t HPB = (size_t)BB*8*PLANE;      // u16x8 elems per branch

    u16x8*    hp8 = (u16x8*)ws;                 ws += 3*HPB*16;
    _Float16* om7 = (_Float16*)ws;              ws += (size_t)BB*3*49*HW*2;
    _Float16* om5 = (_Float16*)ws;              ws += (size_t)BB*3*25*HW*2;
    _Float16* om3 = (_Float16*)ws;              ws += (size_t)BB*3*9*HW*2;
    _Float16* aa  = (_Float16*)ws;              ws += (size_t)BB*CC*HW*2;
    _Float16* mm  = (_Float16*)ws;              ws += (size_t)BB*CC*HW*2;
    _Float16* sm  = (_Float16*)ws;              ws += (size_t)BB*CC*HW*2;
    f16x8*    wtb7= (f16x8*)ws;                 ws += (size_t)49*512*16;
    f16x8*    wbg7= (f16x8*)ws;                 ws += (size_t)49*2*10*64*16;
    f16x8*    wtb5= (f16x8*)ws;                 ws += (size_t)25*512*16;
    f16x8*    wbg5= (f16x8*)ws;                 ws += (size_t)25*2*5*64*16;
    f16x8*    wtb3= (f16x8*)ws;                 ws += (size_t)9*512*16;
    f16x8*    wbg3= (f16x8*)ws;
    _Float16* u   = om7;   // om7 dead after deform_all_k

    hipMemsetAsync(hp8, 0, 3*HPB*16, stream);

    const int npix_blocks = (BB*HW)/256;       // 288
    const int off_blocks  = BB*(HW/256)*2 + BB*(HW/128) + BB*(HW/256); // 1440
    const int dfm_blocks  = 3*BB*(HW/16);      // 13824

    bake_all_k<<<83, 256, 0, stream>>>(
        w_reg_max, w_off_max, w_mod_max,
        w_reg_mid, w_off_mid, w_mod_mid,
        w_reg_small, w_off_small, w_mod_small,
        wtb7, wbg7, wtb5, wbg5, wtb3, wbg3);
    conv_pre_k<<<dim3(npix_blocks, 2, 3), 256, 0, stream>>>(
        x_max, x_mid, x_small, w_pre_max, w_pre_mid, w_pre_small, hp8);

    offmod_all_k<<<off_blocks, 256, 0, stream>>>(
        hp8, wbg7, wbg5, wbg3,
        b_off_max, b_mod_max, b_off_mid, b_mod_mid, b_off_small, b_mod_small,
        om7, om5, om3);

    deform_all_k<<<dfm_blocks, 256, 0, stream>>>(
        hp8, om7, om5, om3, wtb7, wtb5, wtb3, aa, mm, sm);

    conv1x1_k<1><<<dim3(npix_blocks,2), 256, 0, stream>>>(aa, mm, w1,
                                                  nullptr, nullptr, nullptr, u);
    conv1x1_k<2><<<dim3(npix_blocks,2), 256, 0, stream>>>(u, sm, w2,
                                                  x_max, x_mid, x_small, out);
}